// Round 3
// baseline (926.145 us; speedup 1.0000x reference)
//
#include <hip/hip_runtime.h>
#include <hip/hip_bf16.h>

#define N_NODES   50000
#define N_EDGES   500000
#define NHEAD     8
#define NUM_KEYS  8
#define NUM_ETYPES 4
#define NUM_BLOCKS 2
#define N_TARGETS 128
#define NPAD      51200   // 400 tiles * 128
#define NTILES    400
#define LDW       136     // u16 LDS stride: 136*2=272=16*17 -> 16B-aligned rows

typedef unsigned short u16;
typedef unsigned int   u32;
typedef __attribute__((ext_vector_type(8))) short short8;
typedef __attribute__((ext_vector_type(4))) short short4v;
typedef __attribute__((ext_vector_type(4))) float floatx4;

// ---------- bf16 helpers ----------
__device__ __forceinline__ float bflo(u32 u)  { return __uint_as_float(u << 16); }
__device__ __forceinline__ float bfhi(u32 u)  { return __uint_as_float(u & 0xffff0000u); }
__device__ __forceinline__ float bf2f(u16 u)  { return __uint_as_float(((u32)u) << 16); }
__device__ __forceinline__ u16   f2bf(float f){
  u32 u = __float_as_uint(f);
  u += 0x7fffu + ((u >> 16) & 1u);
  return (u16)(u >> 16);
}

// ---------- dtype detector ----------
__global__ void detect_dtype(const u16* raw, int* flag){
  __shared__ int cnt;
  if (threadIdx.x == 0) cnt = 0;
  __syncthreads();
  int sane = 0;
  #pragma unroll
  for (int k = 0; k < 4; k++){
    u16 u = raw[threadIdx.x * 4 + k];
    int e = (u >> 7) & 0xff;
    if (e >= 100 && e <= 145) sane++;
  }
  atomicAdd(&cnt, sane);
  __syncthreads();
  if (threadIdx.x == 0) *flag = (cnt >= 870) ? 1 : 0;
}

__global__ void cvt_f32(const void* src, float* dst, int n, const int* flag){
  int i = blockIdx.x * 256 + threadIdx.x;
  if (i >= n) return;
  dst[i] = (*flag) ? bf2f(((const u16*)src)[i]) : ((const float*)src)[i];
}
__global__ void cvt_bf(const void* src, size_t soff, u16* dst, int n, const int* flag){
  int i = blockIdx.x * 256 + threadIdx.x;
  if (i >= n) return;
  dst[i] = (*flag) ? ((const u16*)src)[soff + i] : f2bf(((const float*)src)[soff + i]);
}

// ---------- key-bucket permutation ----------
__global__ void khist(const int* __restrict__ key_ids, int* __restrict__ kh){
  int n = blockIdx.x * 256 + threadIdx.x;
  if (n < N_NODES) atomicAdd(&kh[key_ids[n]], 1);
}
__global__ void kscan(const int* __restrict__ kh, int* __restrict__ kcur,
                      int* __restrict__ tile_key){
  if (threadIdx.x != 0) return;
  int po[9];
  int off = 0;
  for (int k = 0; k < 8; k++){
    po[k] = off;
    kcur[k] = off;
    off += ((kh[k] + 127) >> 7) << 7;
  }
  po[8] = off;
  for (int t = 0; t < NTILES; t++){
    int row = t << 7;
    int k = 7;
    for (int kk = 0; kk < 8; kk++)
      if (row >= po[kk] && row < po[kk + 1]){ k = kk; break; }
    tile_key[t] = k;
  }
}
__global__ void scatter_perm(const int* __restrict__ key_ids, int* __restrict__ kcur,
                             int* __restrict__ perm, int* __restrict__ invperm){
  int n = blockIdx.x * 256 + threadIdx.x;
  if (n >= N_NODES) return;
  int pos = atomicAdd(&kcur[key_ids[n]], 1);
  perm[pos] = n;
  invperm[n] = pos;
}

// ---------- feat gather into permuted space ----------
__global__ void gather_feat(const void* emb_raw, const int* __restrict__ vid,
                            const int* __restrict__ perm, const int* __restrict__ flag,
                            float* __restrict__ feat, u16* __restrict__ featbf){
  int i = blockIdx.x * 256 + threadIdx.x;          // NPAD*128 exact
  int n = i >> 7, d = i & 127;
  int e = (vid[perm[n]] << 7) + d;
  float v = (*flag) ? bf2f(((const u16*)emb_raw)[e]) : ((const float*)emb_raw)[e];
  feat[i] = v;
  featbf[i] = f2bf(v);
}

// ---------- CSR build (perm space) ----------
__global__ void hist_dst(const int* __restrict__ dst, const int* __restrict__ invp,
                         int* __restrict__ deg){
  int e = blockIdx.x * 256 + threadIdx.x;
  if (e < N_EDGES) atomicAdd(&deg[invp[dst[e]]], 1);
}
__global__ __launch_bounds__(1024) void scan_deg(const int* __restrict__ deg,
                                                 int* __restrict__ rs, int* __restrict__ cur){
  __shared__ int s[1024];
  int t = threadIdx.x;
  int lo = t * 50, hi = lo + 50;                    // 1024*50 = NPAD
  int sum = 0;
  for (int i = lo; i < hi; i++) sum += deg[i];
  s[t] = sum;
  __syncthreads();
  for (int off = 1; off < 1024; off <<= 1){
    int v = (t >= off) ? s[t - off] : 0;
    __syncthreads();
    s[t] += v;
    __syncthreads();
  }
  int run = s[t] - sum;
  for (int i = lo; i < hi; i++){
    rs[i] = run; cur[i] = run;
    run += deg[i];
  }
}
__global__ void scatter_edges(const int* __restrict__ src, const int* __restrict__ dst,
                              const int* __restrict__ et, const int* __restrict__ invp,
                              int* __restrict__ cur, u32* __restrict__ epk){
  int e = blockIdx.x * 256 + threadIdx.x;
  if (e >= N_EDGES) return;
  int pos = atomicAdd(&cur[invp[dst[e]]], 1);
  epk[pos] = ((u32)invp[src[e]] << 2) | (u32)et[e];
}

// ---------- MFMA GEMM, LDS-staged coalesced C store ----------
// C[M,Ncols] = A[M,128] * Bt[Ncols,128]^T; per-row-tile weight select via tkey
__global__ __launch_bounds__(256) void gemm_bt(
    const u16* __restrict__ A, const u16* __restrict__ Bt,
    const int* __restrict__ tkey, u16* __restrict__ C, int Ncols)
{
  __shared__ u16 sc[128 * LDW];
  int m0 = blockIdx.x * 128, n0 = blockIdx.y * 128;
  const u16* Bte = Bt + (tkey ? (size_t)tkey[blockIdx.x] * 16384 : (size_t)0);
  int w = threadIdx.x >> 6, l = threadIdx.x & 63;
  int wm = (w & 1) * 64, wn = (w >> 1) * 64;
  int lr = l & 15, lk = (l >> 4) * 8;
  floatx4 acc[4][4] = {};
  #pragma unroll
  for (int kk = 0; kk < 4; kk++){
    int kbase = kk * 32 + lk;
    short8 af[4], bfr[4];
    #pragma unroll
    for (int i = 0; i < 4; i++)
      af[i] = *(const short8*)(A + (size_t)(m0 + wm + i * 16 + lr) * 128 + kbase);
    #pragma unroll
    for (int j = 0; j < 4; j++)
      bfr[j] = *(const short8*)(Bte + (size_t)(n0 + wn + j * 16 + lr) * 128 + kbase);
    #pragma unroll
    for (int i = 0; i < 4; i++)
      #pragma unroll
      for (int j = 0; j < 4; j++)
        acc[i][j] = __builtin_amdgcn_mfma_f32_16x16x32_bf16(af[i], bfr[j], acc[i][j], 0, 0, 0);
  }
  #pragma unroll
  for (int i = 0; i < 4; i++)
    #pragma unroll
    for (int j = 0; j < 4; j++)
      #pragma unroll
      for (int r = 0; r < 4; r++)
        sc[(wm + i * 16 + (l >> 4) * 4 + r) * LDW + wn + j * 16 + (l & 15)] = f2bf(acc[i][j][r]);
  __syncthreads();
  int tr = threadIdx.x >> 4, tc = (threadIdx.x & 15) * 8;
  #pragma unroll
  for (int it = 0; it < 8; it++){
    int row = tr + it * 16;
    short8 vv = *(const short8*)(sc + row * LDW + tc);
    *(short8*)(C + (size_t)(m0 + row) * Ncols + n0 + tc) = vv;
  }
}

// ---------- fused node GEMM + relu + layernorm + residual ----------
__global__ __launch_bounds__(256) void gemm_h_ln(
    const u16* __restrict__ A, const u16* __restrict__ Bt,
    const int* __restrict__ tkey, const float* __restrict__ gbf,
    float* __restrict__ feat, u16* __restrict__ featbf, int blk)
{
  __shared__ u16 sc[128 * LDW];
  int m0 = blockIdx.x * 128;
  const u16* Bte = Bt + (size_t)tkey[blockIdx.x] * 16384;
  int w = threadIdx.x >> 6, l = threadIdx.x & 63;
  int wm = (w & 1) * 64, wn = (w >> 1) * 64;
  int lr = l & 15, lk = (l >> 4) * 8;
  floatx4 acc[4][4] = {};
  #pragma unroll
  for (int kk = 0; kk < 4; kk++){
    int kbase = kk * 32 + lk;
    short8 af[4], bfr[4];
    #pragma unroll
    for (int i = 0; i < 4; i++)
      af[i] = *(const short8*)(A + (size_t)(m0 + wm + i * 16 + lr) * 128 + kbase);
    #pragma unroll
    for (int j = 0; j < 4; j++)
      bfr[j] = *(const short8*)(Bte + (size_t)(wn + j * 16 + lr) * 128 + kbase);
    #pragma unroll
    for (int i = 0; i < 4; i++)
      #pragma unroll
      for (int j = 0; j < 4; j++)
        acc[i][j] = __builtin_amdgcn_mfma_f32_16x16x32_bf16(af[i], bfr[j], acc[i][j], 0, 0, 0);
  }
  #pragma unroll
  for (int i = 0; i < 4; i++)
    #pragma unroll
    for (int j = 0; j < 4; j++)
      #pragma unroll
      for (int r = 0; r < 4; r++)
        sc[(wm + i * 16 + (l >> 4) * 4 + r) * LDW + wn + j * 16 + (l & 15)] = f2bf(acc[i][j][r]);
  __syncthreads();
  // LN: 2 threads per row, 64 cols each
  int r = threadIdx.x >> 1, half = (threadIdx.x & 1) * 64;
  const u16* srow = sc + r * LDW + half;
  float s1 = 0.f, s2 = 0.f;
  #pragma unroll
  for (int c = 0; c < 64; c++){
    float v = fmaxf(bf2f(srow[c]), 0.f);
    s1 += v; s2 += v * v;
  }
  s1 += __shfl_xor(s1, 1, 64);
  s2 += __shfl_xor(s2, 1, 64);
  float mu = s1 * (1.f / 128.f);
  float var = s2 * (1.f / 128.f) - mu * mu;
  float rstd = rsqrtf(var + 1e-5f);
  int n = m0 + r;
  float* fr = feat + (size_t)n * 128 + half;
  u16*   fb = featbf + (size_t)n * 128 + half;
  const float* gp = gbf + (blk << 7) + half;
  #pragma unroll
  for (int c = 0; c < 64; c += 4){
    float4 fo = *(float4*)(fr + c);
    float y0 = (fmaxf(bf2f(srow[c+0]), 0.f) - mu) * rstd * gp[c+0] + gp[256 + c + 0] + fo.x;
    float y1 = (fmaxf(bf2f(srow[c+1]), 0.f) - mu) * rstd * gp[c+1] + gp[256 + c + 1] + fo.y;
    float y2 = (fmaxf(bf2f(srow[c+2]), 0.f) - mu) * rstd * gp[c+2] + gp[256 + c + 2] + fo.z;
    float y3 = (fmaxf(bf2f(srow[c+3]), 0.f) - mu) * rstd * gp[c+3] + gp[256 + c + 3] + fo.w;
    *(float4*)(fr + c) = make_float4(y0, y1, y2, y3);
    short4v pk; pk.x = (short)f2bf(y0); pk.y = (short)f2bf(y1);
    pk.z = (short)f2bf(y2); pk.w = (short)f2bf(y3);
    *(short4v*)(fb + c) = pk;
  }
}

__device__ __forceinline__ float dot8(uint4 a, uint4 b){
  return bflo(a.x)*bflo(b.x) + bfhi(a.x)*bfhi(b.x)
       + bflo(a.y)*bflo(b.y) + bfhi(a.y)*bfhi(b.y)
       + bflo(a.z)*bflo(b.z) + bfhi(a.z)*bfhi(b.z)
       + bflo(a.w)*bflo(b.w) + bfhi(a.w)*bfhi(b.w);
}

// ---------- single-pass edge attention, one wave per dst node ----------
__global__ __launch_bounds__(256) void edge_attn(
    const u16* __restrict__ q, const u16* __restrict__ kv,
    const int* __restrict__ rs, const int* __restrict__ deg,
    const u32* __restrict__ epk, u16* __restrict__ aggbf)
{
  int n = blockIdx.x * 4 + (threadIdx.x >> 6);
  int l = threadIdx.x & 63;
  int h = l & 7, s = l >> 3;
  const u16* qp = q + (size_t)n * 128 + (h << 4);
  uint4 q0 = *(const uint4*)qp, q1 = *(const uint4*)(qp + 8);
  int e0 = rs[n], cnt = deg[n];
  float z = 0.f;
  float acc[16];
  #pragma unroll
  for (int j = 0; j < 16; j++) acc[j] = 0.f;
  for (int base = 0; base < cnt; base += 8){
    int idx = base + s;
    if (idx < cnt){
      u32 pk = epk[e0 + idx];
      int sn = pk >> 2, et = pk & 3;
      const u16* kp = kv + (size_t)sn * 1024 + (et << 7) + (h << 4);
      uint4 k0 = *(const uint4*)kp, k1 = *(const uint4*)(kp + 8);
      float sc = (dot8(q0, k0) + dot8(q1, k1)) * 0.25f;
      float ew = __expf(fminf(sc, 80.f));
      const u16* vp = kp + 512;
      uint4 v0 = *(const uint4*)vp, v1 = *(const uint4*)(vp + 8);
      z += ew;
      acc[0]  += ew * bflo(v0.x); acc[1]  += ew * bfhi(v0.x);
      acc[2]  += ew * bflo(v0.y); acc[3]  += ew * bfhi(v0.y);
      acc[4]  += ew * bflo(v0.z); acc[5]  += ew * bfhi(v0.z);
      acc[6]  += ew * bflo(v0.w); acc[7]  += ew * bfhi(v0.w);
      acc[8]  += ew * bflo(v1.x); acc[9]  += ew * bfhi(v1.x);
      acc[10] += ew * bflo(v1.y); acc[11] += ew * bfhi(v1.y);
      acc[12] += ew * bflo(v1.z); acc[13] += ew * bfhi(v1.z);
      acc[14] += ew * bflo(v1.w); acc[15] += ew * bfhi(v1.w);
    }
  }
  #pragma unroll
  for (int m = 8; m < 64; m <<= 1){
    z += __shfl_xor(z, m, 64);
    #pragma unroll
    for (int j = 0; j < 16; j++) acc[j] += __shfl_xor(acc[j], m, 64);
  }
  float inv = 1.f / (z + 1e-9f);
  int j0 = s * 2;
  u32 pack = (u32)f2bf(acc[j0] * inv) | ((u32)f2bf(acc[j0 + 1] * inv) << 16);
  *(u32*)(aggbf + (size_t)n * 128 + (h << 4) + j0) = pack;
}

// ---------- target readout ----------
__global__ __launch_bounds__(128) void readout(
    const float* __restrict__ feat, const float* __restrict__ twf,
    const int* __restrict__ key_ids, const int* __restrict__ invp,
    const int* __restrict__ tgt,
    float* __restrict__ outacc, void* dout, const int* __restrict__ flag, int blk)
{
  int t = threadIdx.x;
  int n = tgt[t];
  int key = key_ids[n];
  const float* fr = feat + (size_t)invp[n] * 128;
  const float* wr = twf + (size_t)((blk * 8 + key) << 7);
  float acc = 0.f;
  #pragma unroll
  for (int d = 0; d < 128; d++) acc = fmaf(fr[d], wr[d], acc);
  if (blk == 0){
    outacc[t] = 0.5f * acc;
  } else {
    float r = outacc[t] + 0.5f * acc;
    if (*flag) ((u16*)dout)[t] = f2bf(r);
    else       ((float*)dout)[t] = r;
  }
}

extern "C" void kernel_launch(void* const* d_in, const int* in_sizes, int n_in,
                              void* d_out, int out_size, void* d_ws, size_t ws_size,
                              hipStream_t stream)
{
  const void* emb = d_in[0];
  const void* qw  = d_in[1];
  const void* kw  = d_in[2];
  const void* vw  = d_in[3];
  const void* nw  = d_in[4];
  const void* tw  = d_in[5];
  const void* lg  = d_in[6];
  const void* lb  = d_in[7];
  const int* value_ids = (const int*)d_in[8];
  const int* key_ids   = (const int*)d_in[9];
  const int* srcp  = (const int*)d_in[10];
  const int* dstp  = (const int*)d_in[11];
  const int* etp   = (const int*)d_in[12];
  const int* tgt   = (const int*)d_in[13];

  char* p = (char*)d_ws;
  auto carve = [&](size_t bytes)->char*{
    char* r = p; p += (bytes + 255) & ~(size_t)255; return r;
  };
  int*   flag    = (int*)  carve(4);
  float* featp   = (float*)carve((size_t)NPAD * 128 * 4);
  u16*   featbf  = (u16*)  carve((size_t)NPAD * 128 * 2);
  u16*   qwc     = (u16*)  carve((size_t)2 * 1024 * 128 * 2);
  u16*   kvw     = (u16*)  carve((size_t)2 * 1024 * 128 * 2);
  u16*   nwc     = (u16*)  carve((size_t)2 * 1024 * 128 * 2);
  float* twf     = (float*)carve((size_t)2048 * 4);
  float* gbf     = (float*)carve((size_t)512 * 4);
  int*   kh      = (int*)  carve(8 * 4);
  int*   kcur    = (int*)  carve(8 * 4);
  int*   tile_key= (int*)  carve(NTILES * 4);
  int*   perm    = (int*)  carve((size_t)NPAD * 4);
  int*   invperm = (int*)  carve((size_t)N_NODES * 4);
  int*   deg     = (int*)  carve((size_t)NPAD * 4);
  int*   rsx     = (int*)  carve((size_t)NPAD * 4);
  int*   cur     = (int*)  carve((size_t)NPAD * 4);
  u32*   epk     = (u32*)  carve((size_t)N_EDGES * 4);
  u16*   qbuf    = (u16*)  carve((size_t)NPAD * 128 * 2);
  u16*   kvbuf   = (u16*)  carve((size_t)NPAD * 1024 * 2);
  u16*   aggbf   = (u16*)  carve((size_t)NPAD * 128 * 2);
  float* outacc  = (float*)carve((size_t)N_TARGETS * 4);
  (void)ws_size; (void)n_in; (void)in_sizes; (void)out_size;

  detect_dtype<<<1, 256, 0, stream>>>((const u16*)emb, flag);

  auto cbf = [&](const void* s, size_t so, u16* d, int n){
    cvt_bf<<<(n + 255) / 256, 256, 0, stream>>>(s, so, d, n, flag);
  };
  cbf(qw, 0, qwc, 2 * 1024 * 128);
  cbf(nw, 0, nwc, 2 * 1024 * 128);
  for (int b = 0; b < 2; b++){
    cbf(kw, (size_t)b * 512 * 128, kvw + (size_t)b * 1024 * 128,             512 * 128);
    cbf(vw, (size_t)b * 512 * 128, kvw + (size_t)b * 1024 * 128 + 512 * 128, 512 * 128);
  }
  cvt_f32<<<8, 256, 0, stream>>>(tw, twf, 2048, flag);
  cvt_f32<<<1, 256, 0, stream>>>(lg, gbf, 256, flag);
  cvt_f32<<<1, 256, 0, stream>>>(lb, gbf + 256, 256, flag);

  // key-bucket permutation
  hipMemsetAsync(kh, 0, 8 * 4, stream);
  hipMemsetAsync(perm, 0, (size_t)NPAD * 4, stream);
  khist<<<(N_NODES + 255) / 256, 256, 0, stream>>>(key_ids, kh);
  kscan<<<1, 64, 0, stream>>>(kh, kcur, tile_key);
  scatter_perm<<<(N_NODES + 255) / 256, 256, 0, stream>>>(key_ids, kcur, perm, invperm);

  gather_feat<<<(NPAD * 128) / 256, 256, 0, stream>>>(emb, value_ids, perm, flag, featp, featbf);

  // CSR in perm space
  hipMemsetAsync(deg, 0, (size_t)NPAD * 4, stream);
  const int eg = (N_EDGES + 255) / 256;
  hist_dst<<<eg, 256, 0, stream>>>(dstp, invperm, deg);
  scan_deg<<<1, 1024, 0, stream>>>(deg, rsx, cur);
  scatter_edges<<<eg, 256, 0, stream>>>(srcp, dstp, etp, invperm, cur, epk);

  for (int b = 0; b < NUM_BLOCKS; b++){
    gemm_bt<<<dim3(NTILES, 1), 256, 0, stream>>>(featbf, qwc + (size_t)b * 1024 * 128,
                                                 tile_key, qbuf, 128);
    gemm_bt<<<dim3(NTILES, 8), 256, 0, stream>>>(featbf, kvw + (size_t)b * 1024 * 128,
                                                 nullptr, kvbuf, 1024);
    edge_attn<<<NPAD / 4, 256, 0, stream>>>(qbuf, kvbuf, rsx, deg, epk, aggbf);
    gemm_h_ln<<<NTILES, 256, 0, stream>>>(aggbf, nwc + (size_t)b * 1024 * 128,
                                          tile_key, gbf, featp, featbf, b);
    readout<<<1, 128, 0, stream>>>(featp, twf, key_ids, invperm, tgt, outacc, d_out, flag, b);
  }
}

// Round 5
// 599.035 us; speedup vs baseline: 1.5461x; 1.5461x over previous
//
#include <hip/hip_runtime.h>
#include <hip/hip_bf16.h>

#define N_NODES   50000
#define N_EDGES   500000
#define NHEAD     8
#define NUM_KEYS  8
#define NUM_ETYPES 4
#define NUM_BLOCKS 2
#define N_TARGETS 128
#define NPAD      51200   // 400 tiles * 128
#define NTILES    400
#define NBLK      196     // ceil(N_NODES/256)
#define LDW       136     // u16 LDS stride (16B-aligned rows)
#define LDWF      132     // f32 LDS stride (16B-aligned, odd/33*4 -> conflict-light)

typedef unsigned short u16;
typedef unsigned int   u32;
typedef __attribute__((ext_vector_type(8))) short short8;
typedef __attribute__((ext_vector_type(4))) short short4v;
typedef __attribute__((ext_vector_type(4))) float floatx4;

// ---------- bf16 helpers ----------
__device__ __forceinline__ float bflo(u32 u)  { return __uint_as_float(u << 16); }
__device__ __forceinline__ float bfhi(u32 u)  { return __uint_as_float(u & 0xffff0000u); }
__device__ __forceinline__ float bf2f(u16 u)  { return __uint_as_float(((u32)u) << 16); }
__device__ __forceinline__ u16   f2bf(float f){
  u32 u = __float_as_uint(f);
  u += 0x7fffu + ((u >> 16) & 1u);
  return (u16)(u >> 16);
}

// ---------- dtype detector ----------
__global__ void detect_dtype(const u16* raw, int* flag){
  __shared__ int cnt;
  if (threadIdx.x == 0) cnt = 0;
  __syncthreads();
  int sane = 0;
  #pragma unroll
  for (int k = 0; k < 4; k++){
    u16 u = raw[threadIdx.x * 4 + k];
    int e = (u >> 7) & 0xff;
    if (e >= 100 && e <= 145) sane++;
  }
  atomicAdd(&cnt, sane);
  __syncthreads();
  if (threadIdx.x == 0) *flag = (cnt >= 870) ? 1 : 0;
}

__global__ void cvt_f32(const void* src, float* dst, int n, const int* flag){
  int i = blockIdx.x * 256 + threadIdx.x;
  if (i >= n) return;
  dst[i] = (*flag) ? bf2f(((const u16*)src)[i]) : ((const float*)src)[i];
}
__global__ void cvt_bf(const void* src, size_t soff, u16* dst, int n, const int* flag){
  int i = blockIdx.x * 256 + threadIdx.x;
  if (i >= n) return;
  dst[i] = (*flag) ? ((const u16*)src)[soff + i] : f2bf(((const float*)src)[soff + i]);
}

// ---------- contention-free, deterministic key-bucket counting sort ----------
__global__ void khist_blk(const int* __restrict__ key_ids, int* __restrict__ blkcnt){
  __shared__ int c[8];
  int t = threadIdx.x, b = blockIdx.x;
  if (t < 8) c[t] = 0;
  __syncthreads();
  int n = b * 256 + t;
  if (n < N_NODES) atomicAdd(&c[key_ids[n]], 1);
  __syncthreads();
  if (t < 8) blkcnt[t * NBLK + b] = c[t];
}
__global__ void kscan2(const int* __restrict__ blkcnt, int* __restrict__ base,
                       int* __restrict__ tile_key){
  __shared__ int po[8];
  __shared__ int tot[8];
  int t = threadIdx.x;  // 64 threads
  if (t < 8){
    int s = 0;
    for (int b = 0; b < NBLK; b++) s += blkcnt[t * NBLK + b];
    tot[t] = s;
  }
  __syncthreads();
  if (t == 0){
    int off = 0;
    for (int k = 0; k < 8; k++){ po[k] = off; off += ((tot[k] + 127) >> 7) << 7; }
  }
  __syncthreads();
  if (t < 8){
    int run = po[t];
    for (int b = 0; b < NBLK; b++){ base[t * NBLK + b] = run; run += blkcnt[t * NBLK + b]; }
  }
  for (int tt = t; tt < NTILES; tt += 64){
    int row = tt << 7, k = 7;
    for (int kk = 1; kk < 8; kk++)
      if (row < po[kk]){ k = kk - 1; break; }
    tile_key[tt] = k;
  }
}
// deterministic rank: prefix count within block (no atomics)
__global__ void scatter_perm2(const int* __restrict__ key_ids, const int* __restrict__ base,
                              int* __restrict__ perm, int* __restrict__ invperm){
  __shared__ unsigned char keyarr[256];
  int t = threadIdx.x, b = blockIdx.x;
  int n = b * 256 + t;
  int key = (n < N_NODES) ? key_ids[n] : 8;
  keyarr[t] = (unsigned char)key;
  __syncthreads();
  if (n >= N_NODES) return;
  int rank = 0;
  for (int j = 0; j < t; j++) rank += (keyarr[j] == (unsigned char)key);
  int pos = base[key * NBLK + b] + rank;
  perm[pos] = n;
  invperm[n] = pos;
}

// ---------- feat gather: f32 + hi/lo bf16 ----------
__global__ void gather_feat(const void* emb_raw, const int* __restrict__ vid,
                            const int* __restrict__ perm, const int* __restrict__ flag,
                            float* __restrict__ feat, u16* __restrict__ fhi,
                            u16* __restrict__ flo){
  int i = blockIdx.x * 256 + threadIdx.x;          // NPAD*128 exact
  int n = i >> 7, d = i & 127;
  int e = (vid[perm[n]] << 7) + d;
  float v = (*flag) ? bf2f(((const u16*)emb_raw)[e]) : ((const float*)emb_raw)[e];
  feat[i] = v;
  u16 h = f2bf(v);
  fhi[i] = h;
  flo[i] = f2bf(v - bf2f(h));
}

// ---------- CSR build (perm space) ----------
__global__ void hist_dst(const int* __restrict__ dst, const int* __restrict__ invp,
                         int* __restrict__ deg){
  int e = blockIdx.x * 256 + threadIdx.x;
  if (e < N_EDGES) atomicAdd(&deg[invp[dst[e]]], 1);
}
__global__ __launch_bounds__(1024) void scan_deg(const int* __restrict__ deg,
                                                 int* __restrict__ rs, int* __restrict__ cur){
  __shared__ int s[1024];
  int t = threadIdx.x;
  int lo = t * 50, hi = lo + 50;                    // 1024*50 = NPAD
  int sum = 0;
  for (int i = lo; i < hi; i++) sum += deg[i];
  s[t] = sum;
  __syncthreads();
  for (int off = 1; off < 1024; off <<= 1){
    int v = (t >= off) ? s[t - off] : 0;
    __syncthreads();
    s[t] += v;
    __syncthreads();
  }
  int run = s[t] - sum;
  for (int i = lo; i < hi; i++){
    rs[i] = run; cur[i] = run;
    run += deg[i];
  }
}
__global__ void scatter_edges(const int* __restrict__ src, const int* __restrict__ dst,
                              const int* __restrict__ et, const int* __restrict__ invp,
                              int* __restrict__ cur, u32* __restrict__ epk){
  int e = blockIdx.x * 256 + threadIdx.x;
  if (e >= N_EDGES) return;
  int pos = atomicAdd(&cur[invp[dst[e]]], 1);
  epk[pos] = ((u32)invp[src[e]] << 2) | (u32)et[e];
}

// ---------- MFMA GEMM (A = hi/lo double-bf16), bf16 C, LDS-staged store ----------
__global__ __launch_bounds__(256) void gemm_bt2(
    const u16* __restrict__ Ahi, const u16* __restrict__ Alo,
    const u16* __restrict__ Bt, const int* __restrict__ tkey,
    u16* __restrict__ C, int Ncols)
{
  __shared__ u16 sc[128 * LDW];
  int m0 = blockIdx.x * 128, n0 = blockIdx.y * 128;
  const u16* Bte = Bt + (tkey ? (size_t)tkey[blockIdx.x] * 16384 : (size_t)0);
  int w = threadIdx.x >> 6, l = threadIdx.x & 63;
  int wm = (w & 1) * 64, wn = (w >> 1) * 64;
  int lr = l & 15, lk = (l >> 4) * 8;
  floatx4 acc[4][4] = {};
  #pragma unroll
  for (int kk = 0; kk < 4; kk++){
    int kbase = kk * 32 + lk;
    short8 ah[4], al[4], bfr[4];
    #pragma unroll
    for (int i = 0; i < 4; i++){
      size_t off = (size_t)(m0 + wm + i * 16 + lr) * 128 + kbase;
      ah[i] = *(const short8*)(Ahi + off);
      al[i] = *(const short8*)(Alo + off);
    }
    #pragma unroll
    for (int j = 0; j < 4; j++)
      bfr[j] = *(const short8*)(Bte + (size_t)(n0 + wn + j * 16 + lr) * 128 + kbase);
    #pragma unroll
    for (int i = 0; i < 4; i++)
      #pragma unroll
      for (int j = 0; j < 4; j++){
        acc[i][j] = __builtin_amdgcn_mfma_f32_16x16x32_bf16(ah[i], bfr[j], acc[i][j], 0, 0, 0);
        acc[i][j] = __builtin_amdgcn_mfma_f32_16x16x32_bf16(al[i], bfr[j], acc[i][j], 0, 0, 0);
      }
  }
  #pragma unroll
  for (int i = 0; i < 4; i++)
    #pragma unroll
    for (int j = 0; j < 4; j++)
      #pragma unroll
      for (int r = 0; r < 4; r++)
        sc[(wm + i * 16 + (l >> 4) * 4 + r) * LDW + wn + j * 16 + (l & 15)] = f2bf(acc[i][j][r]);
  __syncthreads();
  int tr = threadIdx.x >> 4, tc = (threadIdx.x & 15) * 8;
  #pragma unroll
  for (int it = 0; it < 8; it++){
    int row = tr + it * 16;
    short8 vv = *(const short8*)(sc + row * LDW + tc);
    *(short8*)(C + (size_t)(m0 + row) * Ncols + n0 + tc) = vv;
  }
}

// ---------- fused node GEMM (hi/lo A) + relu + f32 LN + residual; 64-row tiles ----------
__global__ __launch_bounds__(256) void gemm_h_ln(
    const u16* __restrict__ Ahi, const u16* __restrict__ Alo,
    const u16* __restrict__ Bt, const int* __restrict__ tkey,
    const float* __restrict__ gbf,
    float* __restrict__ feat, u16* __restrict__ fhi, u16* __restrict__ flo, int blk)
{
  __shared__ float scf[64 * LDWF];
  int m0 = blockIdx.x * 64;
  const u16* Bte = Bt + (size_t)tkey[blockIdx.x >> 1] * 16384;
  int w = threadIdx.x >> 6, l = threadIdx.x & 63;
  int wn = w * 32;
  int lr = l & 15, lk = (l >> 4) * 8;
  floatx4 acc[4][2] = {};
  #pragma unroll
  for (int kk = 0; kk < 4; kk++){
    int kbase = kk * 32 + lk;
    short8 ah[4], al[4], bfr[2];
    #pragma unroll
    for (int i = 0; i < 4; i++){
      size_t off = (size_t)(m0 + i * 16 + lr) * 128 + kbase;
      ah[i] = *(const short8*)(Ahi + off);
      al[i] = *(const short8*)(Alo + off);
    }
    #pragma unroll
    for (int j = 0; j < 2; j++)
      bfr[j] = *(const short8*)(Bte + (size_t)(wn + j * 16 + lr) * 128 + kbase);
    #pragma unroll
    for (int i = 0; i < 4; i++)
      #pragma unroll
      for (int j = 0; j < 2; j++){
        acc[i][j] = __builtin_amdgcn_mfma_f32_16x16x32_bf16(ah[i], bfr[j], acc[i][j], 0, 0, 0);
        acc[i][j] = __builtin_amdgcn_mfma_f32_16x16x32_bf16(al[i], bfr[j], acc[i][j], 0, 0, 0);
      }
  }
  #pragma unroll
  for (int i = 0; i < 4; i++)
    #pragma unroll
    for (int j = 0; j < 2; j++)
      #pragma unroll
      for (int r = 0; r < 4; r++)
        scf[(i * 16 + (l >> 4) * 4 + r) * LDWF + wn + j * 16 + (l & 15)] = acc[i][j][r];
  __syncthreads();
  // LN in f32: 4 threads per row, 32 cols each
  int r = threadIdx.x >> 2, q4 = (threadIdx.x & 3) * 32;
  const float* srow = scf + r * LDWF + q4;
  float s1 = 0.f, s2 = 0.f;
  #pragma unroll
  for (int c = 0; c < 32; c++){
    float v = fmaxf(srow[c], 0.f);
    s1 += v; s2 += v * v;
  }
  s1 += __shfl_xor(s1, 1, 64); s1 += __shfl_xor(s1, 2, 64);
  s2 += __shfl_xor(s2, 1, 64); s2 += __shfl_xor(s2, 2, 64);
  float mu = s1 * (1.f / 128.f);
  float var = s2 * (1.f / 128.f) - mu * mu;
  float rstd = rsqrtf(var + 1e-5f);
  int n = m0 + r;
  float* fr = feat + (size_t)n * 128 + q4;
  u16*  fhp = fhi + (size_t)n * 128 + q4;
  u16*  flp = flo + (size_t)n * 128 + q4;
  const float* gp = gbf + (blk << 7) + q4;
  #pragma unroll
  for (int c = 0; c < 32; c += 4){
    float4 fo = *(float4*)(fr + c);
    float y0 = (fmaxf(srow[c+0], 0.f) - mu) * rstd * gp[c+0] + gp[256 + c + 0] + fo.x;
    float y1 = (fmaxf(srow[c+1], 0.f) - mu) * rstd * gp[c+1] + gp[256 + c + 1] + fo.y;
    float y2 = (fmaxf(srow[c+2], 0.f) - mu) * rstd * gp[c+2] + gp[256 + c + 2] + fo.z;
    float y3 = (fmaxf(srow[c+3], 0.f) - mu) * rstd * gp[c+3] + gp[256 + c + 3] + fo.w;
    *(float4*)(fr + c) = make_float4(y0, y1, y2, y3);
    u16 h0 = f2bf(y0), h1 = f2bf(y1), h2 = f2bf(y2), h3 = f2bf(y3);
    short4v ph; ph.x = (short)h0; ph.y = (short)h1; ph.z = (short)h2; ph.w = (short)h3;
    *(short4v*)(fhp + c) = ph;
    short4v pl;
    pl.x = (short)f2bf(y0 - bf2f(h0)); pl.y = (short)f2bf(y1 - bf2f(h1));
    pl.z = (short)f2bf(y2 - bf2f(h2)); pl.w = (short)f2bf(y3 - bf2f(h3));
    *(short4v*)(flp + c) = pl;
  }
}

__device__ __forceinline__ float dot8(uint4 a, uint4 b){
  return bflo(a.x)*bflo(b.x) + bfhi(a.x)*bfhi(b.x)
       + bflo(a.y)*bflo(b.y) + bfhi(a.y)*bfhi(b.y)
       + bflo(a.z)*bflo(b.z) + bfhi(a.z)*bfhi(b.z)
       + bflo(a.w)*bflo(b.w) + bfhi(a.w)*bfhi(b.w);
}

// ---------- single-pass edge attention, one wave per dst node; agg -> hi/lo ----------
__global__ __launch_bounds__(256) void edge_attn(
    const u16* __restrict__ q, const u16* __restrict__ kv,
    const int* __restrict__ rs, const int* __restrict__ deg,
    const u32* __restrict__ epk, u16* __restrict__ agghi, u16* __restrict__ agglo)
{
  int n = blockIdx.x * 4 + (threadIdx.x >> 6);
  int l = threadIdx.x & 63;
  int h = l & 7, s = l >> 3;
  const u16* qp = q + (size_t)n * 128 + (h << 4);
  uint4 q0 = *(const uint4*)qp, q1 = *(const uint4*)(qp + 8);
  int e0 = rs[n], cnt = deg[n];
  float z = 0.f;
  float acc[16];
  #pragma unroll
  for (int j = 0; j < 16; j++) acc[j] = 0.f;
  for (int base = 0; base < cnt; base += 8){
    int idx = base + s;
    if (idx < cnt){
      u32 pk = epk[e0 + idx];
      int sn = pk >> 2, et = pk & 3;
      const u16* kp = kv + (size_t)sn * 1024 + (et << 7) + (h << 4);
      uint4 k0 = *(const uint4*)kp, k1 = *(const uint4*)(kp + 8);
      float sc = (dot8(q0, k0) + dot8(q1, k1)) * 0.25f;
      float ew = __expf(fminf(sc, 80.f));
      const u16* vp = kp + 512;
      uint4 v0 = *(const uint4*)vp, v1 = *(const uint4*)(vp + 8);
      z += ew;
      acc[0]  += ew * bflo(v0.x); acc[1]  += ew * bfhi(v0.x);
      acc[2]  += ew * bflo(v0.y); acc[3]  += ew * bfhi(v0.y);
      acc[4]  += ew * bflo(v0.z); acc[5]  += ew * bfhi(v0.z);
      acc[6]  += ew * bflo(v0.w); acc[7]  += ew * bfhi(v0.w);
      acc[8]  += ew * bflo(v1.x); acc[9]  += ew * bfhi(v1.x);
      acc[10] += ew * bflo(v1.y); acc[11] += ew * bfhi(v1.y);
      acc[12] += ew * bflo(v1.z); acc[13] += ew * bfhi(v1.z);
      acc[14] += ew * bflo(v1.w); acc[15] += ew * bfhi(v1.w);
    }
  }
  #pragma unroll
  for (int m = 8; m < 64; m <<= 1){
    z += __shfl_xor(z, m, 64);
    #pragma unroll
    for (int j = 0; j < 16; j++) acc[j] += __shfl_xor(acc[j], m, 64);
  }
  float inv = 1.f / (z + 1e-9f);
  int j0 = s * 2;
  float x0 = acc[j0] * inv, x1 = acc[j0 + 1] * inv;
  u16 h0 = f2bf(x0), h1 = f2bf(x1);
  size_t o = (size_t)n * 128 + (h << 4) + j0;
  *(u32*)(agghi + o) = (u32)h0 | ((u32)h1 << 16);
  *(u32*)(agglo + o) = (u32)f2bf(x0 - bf2f(h0)) | ((u32)f2bf(x1 - bf2f(h1)) << 16);
}

// ---------- target readout ----------
__global__ __launch_bounds__(128) void readout(
    const float* __restrict__ feat, const float* __restrict__ twf,
    const int* __restrict__ key_ids, const int* __restrict__ invp,
    const int* __restrict__ tgt,
    float* __restrict__ outacc, void* dout, const int* __restrict__ flag, int blk)
{
  int t = threadIdx.x;
  int n = tgt[t];
  int key = key_ids[n];
  const float* fr = feat + (size_t)invp[n] * 128;
  const float* wr = twf + (size_t)((blk * 8 + key) << 7);
  float acc = 0.f;
  #pragma unroll
  for (int d = 0; d < 128; d++) acc = fmaf(fr[d], wr[d], acc);
  if (blk == 0){
    outacc[t] = 0.5f * acc;
  } else {
    float r = outacc[t] + 0.5f * acc;
    if (*flag) ((u16*)dout)[t] = f2bf(r);
    else       ((float*)dout)[t] = r;
  }
}

extern "C" void kernel_launch(void* const* d_in, const int* in_sizes, int n_in,
                              void* d_out, int out_size, void* d_ws, size_t ws_size,
                              hipStream_t stream)
{
  const void* emb = d_in[0];
  const void* qw  = d_in[1];
  const void* kw  = d_in[2];
  const void* vw  = d_in[3];
  const void* nw  = d_in[4];
  const void* tw  = d_in[5];
  const void* lg  = d_in[6];
  const void* lb  = d_in[7];
  const int* value_ids = (const int*)d_in[8];
  const int* key_ids   = (const int*)d_in[9];
  const int* srcp  = (const int*)d_in[10];
  const int* dstp  = (const int*)d_in[11];
  const int* etp   = (const int*)d_in[12];
  const int* tgt   = (const int*)d_in[13];

  char* p = (char*)d_ws;
  auto carve = [&](size_t bytes)->char*{
    char* r = p; p += (bytes + 255) & ~(size_t)255; return r;
  };
  int*   flag    = (int*)  carve(4);
  float* featp   = (float*)carve((size_t)NPAD * 128 * 4);
  u16*   feathi  = (u16*)  carve((size_t)NPAD * 128 * 2);
  u16*   featlo  = (u16*)  carve((size_t)NPAD * 128 * 2);
  u16*   qwc     = (u16*)  carve((size_t)2 * 1024 * 128 * 2);
  u16*   kvw     = (u16*)  carve((size_t)2 * 1024 * 128 * 2);
  u16*   nwc     = (u16*)  carve((size_t)2 * 1024 * 128 * 2);
  float* twf     = (float*)carve((size_t)2048 * 4);
  float* gbf     = (float*)carve((size_t)512 * 4);
  int*   blkcnt  = (int*)  carve((size_t)8 * NBLK * 4);
  int*   kbase   = (int*)  carve((size_t)8 * NBLK * 4);
  int*   tile_key= (int*)  carve(NTILES * 4);
  int*   perm    = (int*)  carve((size_t)NPAD * 4);
  int*   invperm = (int*)  carve((size_t)N_NODES * 4);
  int*   deg     = (int*)  carve((size_t)NPAD * 4);
  int*   rsx     = (int*)  carve((size_t)NPAD * 4);
  int*   cur     = (int*)  carve((size_t)NPAD * 4);
  u32*   epk     = (u32*)  carve((size_t)N_EDGES * 4);
  u16*   qbuf    = (u16*)  carve((size_t)NPAD * 128 * 2);
  u16*   kvbuf   = (u16*)  carve((size_t)NPAD * 1024 * 2);
  u16*   agghi   = (u16*)  carve((size_t)NPAD * 128 * 2);
  u16*   agglo   = (u16*)  carve((size_t)NPAD * 128 * 2);
  float* outacc  = (float*)carve((size_t)N_TARGETS * 4);
  (void)ws_size; (void)n_in; (void)in_sizes; (void)out_size;

  detect_dtype<<<1, 256, 0, stream>>>((const u16*)emb, flag);

  auto cbf = [&](const void* s, size_t so, u16* d, int n){
    cvt_bf<<<(n + 255) / 256, 256, 0, stream>>>(s, so, d, n, flag);
  };
  cbf(qw, 0, qwc, 2 * 1024 * 128);
  cbf(nw, 0, nwc, 2 * 1024 * 128);
  for (int b = 0; b < 2; b++){
    cbf(kw, (size_t)b * 512 * 128, kvw + (size_t)b * 1024 * 128,             512 * 128);
    cbf(vw, (size_t)b * 512 * 128, kvw + (size_t)b * 1024 * 128 + 512 * 128, 512 * 128);
  }
  cvt_f32<<<8, 256, 0, stream>>>(tw, twf, 2048, flag);
  cvt_f32<<<1, 256, 0, stream>>>(lg, gbf, 256, flag);
  cvt_f32<<<1, 256, 0, stream>>>(lb, gbf + 256, 256, flag);

  // deterministic key-bucket counting sort
  hipMemsetAsync(perm, 0, (size_t)NPAD * 4, stream);
  khist_blk<<<NBLK, 256, 0, stream>>>(key_ids, blkcnt);
  kscan2<<<1, 64, 0, stream>>>(blkcnt, kbase, tile_key);
  scatter_perm2<<<NBLK, 256, 0, stream>>>(key_ids, kbase, perm, invperm);

  gather_feat<<<(NPAD * 128) / 256, 256, 0, stream>>>(emb, value_ids, perm, flag,
                                                      featp, feathi, featlo);

  // CSR in perm space
  hipMemsetAsync(deg, 0, (size_t)NPAD * 4, stream);
  const int eg = (N_EDGES + 255) / 256;
  hist_dst<<<eg, 256, 0, stream>>>(dstp, invperm, deg);
  scan_deg<<<1, 1024, 0, stream>>>(deg, rsx, cur);
  scatter_edges<<<eg, 256, 0, stream>>>(srcp, dstp, etp, invperm, cur, epk);

  for (int b = 0; b < NUM_BLOCKS; b++){
    gemm_bt2<<<dim3(NTILES, 1), 256, 0, stream>>>(feathi, featlo,
                                                  qwc + (size_t)b * 1024 * 128,
                                                  tile_key, qbuf, 128);
    gemm_bt2<<<dim3(NTILES, 8), 256, 0, stream>>>(feathi, featlo,
                                                  kvw + (size_t)b * 1024 * 128,
                                                  nullptr, kvbuf, 1024);
    edge_attn<<<NPAD / 4, 256, 0, stream>>>(qbuf, kvbuf, rsx, deg, epk, agghi, agglo);
    gemm_h_ln<<<NPAD / 64, 256, 0, stream>>>(agghi, agglo,
                                             nwc + (size_t)b * 1024 * 128,
                                             tile_key, gbf, featp, feathi, featlo, b);
    readout<<<1, 128, 0, stream>>>(featp, twf, key_ids, invperm, tgt, outacc, d_out, flag, b);
  }
}